// Round 17
// baseline (117.274 us; speedup 1.0000x reference)
//
#include <hip/hip_runtime.h>
#include <hip/hip_bf16.h>
#include <math.h>

typedef __bf16 bf16_t;
typedef __attribute__((ext_vector_type(8))) __bf16 bf16x8;
typedef __attribute__((ext_vector_type(4))) __bf16 bf16x4;
typedef __attribute__((ext_vector_type(4))) float f32x4;

#define B_DIM 2
#define S_DIM 2048
#define H_DIM 16
#define DK 64
#define DM 1024
#define KDIM 1024

#define MFMA(a, b, c) __builtin_amdgcn_mfma_f32_16x16x32_bf16((a), (b), (c), 0, 0, 0)

__device__ __forceinline__ void gload_lds16(const bf16_t* g, bf16_t* l) {
    __builtin_amdgcn_global_load_lds(
        (const __attribute__((address_space(1))) void*)g,
        (__attribute__((address_space(3))) void*)l, 16, 0, 0);
}

// ---------------- fp32 -> bf16 convert: x + 4 weights in ONE launch ----------------
__global__ void cvt_all(const float* __restrict__ x,
                        const float* __restrict__ wq, const float* __restrict__ wk,
                        const float* __restrict__ wv, const float* __restrict__ wo,
                        bf16_t* __restrict__ xb,
                        bf16_t* __restrict__ wqb, bf16_t* __restrict__ wkb,
                        bf16_t* __restrict__ wvb, bf16_t* __restrict__ wob) {
    const long NX = (long)B_DIM * S_DIM * DM;       // 4194304
    const long i = ((long)blockIdx.x * 256 + threadIdx.x) * 4;
    const float* s; bf16_t* d; long off;
    if (i < NX) { s = x; d = xb; off = i; }
    else {
        const long j = i - NX;
        const int wsel = (int)(j >> 20);            // NW = 1<<20
        off = j & ((1L << 20) - 1);
        switch (wsel) {
            case 0: s = wq; d = wqb; break;
            case 1: s = wk; d = wkb; break;
            case 2: s = wv; d = wvb; break;
            default: s = wo; d = wob; break;
        }
    }
    float4 v = *reinterpret_cast<const float4*>(s + off);
    bf16x4 o;
    o[0] = (__bf16)v.x; o[1] = (__bf16)v.y; o[2] = (__bf16)v.z; o[3] = (__bf16)v.w;
    *reinterpret_cast<bf16x4*>(d + off) = o;
}

// ---------------- GEMM: Y[m,n] = sum_k A[m,k] * B[n,k]  (B^T layout) ----------------
// (unchanged from R12: BK=64 XOR-swizzled K-loop + coalesced epilogues)
template <int MODE>
__global__ __launch_bounds__(256)
void gemm_bt(const bf16_t* __restrict__ A,
             const bf16_t* __restrict__ B0,
             const bf16_t* __restrict__ B1,
             const bf16_t* __restrict__ B2,
             bf16_t* __restrict__ outQ,
             bf16_t* __restrict__ outK,
             bf16_t* __restrict__ outVt,
             float* __restrict__ outF,
             const int* __restrict__ pos) {
    constexpr int CP = 136;
    constexpr int SELEMS = (MODE == 0) ? (128 * CP) : 16384;
    __shared__ bf16_t smem[SELEMS];
    bf16_t* As = smem;            // [128][64] swizzled
    bf16_t* Bs = smem + 8192;     // [128][64] swizzled
    bf16_t* Cs = smem;            // epilogue overlay

    const int t = threadIdx.x;
    const int z = blockIdx.z;
    const bf16_t* Bm = (MODE == 0) ? (z == 0 ? B0 : (z == 1 ? B1 : B2)) : B0;

    const int m0 = blockIdx.x * 128;
    const int n0 = blockIdx.y * 128;
    const int lane = t & 63;
    const int w = t >> 6;
    const int wr = w >> 1;
    const int wc = w & 1;

    f32x4 acc[4][4] = {};

    const bf16_t* Ag = A + (size_t)m0 * KDIM;
    const bf16_t* Bg = Bm + (size_t)n0 * KDIM;

    const int rr = lane & 15;
    const int ko = (lane >> 4) * 8;

    int rI[4], cI[4];
#pragma unroll
    for (int c = 0; c < 4; ++c) {
        const int i = t + c * 256;
        rI[c] = i >> 3;
        cI[c] = ((i & 7) ^ (rI[c] & 7)) * 8;
    }

    for (int k0 = 0; k0 < KDIM; k0 += 64) {
#pragma unroll
        for (int c = 0; c < 4; ++c) {
            const int i = t + c * 256;
            gload_lds16(Ag + (size_t)rI[c] * KDIM + k0 + cI[c], &As[i * 8]);
        }
#pragma unroll
        for (int c = 0; c < 4; ++c) {
            const int i = t + c * 256;
            gload_lds16(Bg + (size_t)rI[c] * KDIM + k0 + cI[c], &Bs[i * 8]);
        }
        __syncthreads();

        bf16x8 af[2][4], bfr[2][4];
#pragma unroll
        for (int kk = 0; kk < 2; ++kk) {
#pragma unroll
            for (int m = 0; m < 4; ++m) {
                const int r = wr * 64 + m * 16 + rr;
                af[kk][m] = *reinterpret_cast<const bf16x8*>(
                    &As[r * 64 + ((kk * 32 + ko) ^ ((r & 7) * 8))]);
            }
#pragma unroll
            for (int n = 0; n < 4; ++n) {
                const int r = wc * 64 + n * 16 + rr;
                bfr[kk][n] = *reinterpret_cast<const bf16x8*>(
                    &Bs[r * 64 + ((kk * 32 + ko) ^ ((r & 7) * 8))]);
            }
        }
        __builtin_amdgcn_s_setprio(1);
#pragma unroll
        for (int kk = 0; kk < 2; ++kk)
#pragma unroll
            for (int m = 0; m < 4; ++m)
#pragma unroll
                for (int n = 0; n < 4; ++n)
                    acc[m][n] = MFMA(af[kk][m], bfr[kk][n], acc[m][n]);
        __builtin_amdgcn_s_setprio(0);
        __syncthreads();
    }

    const int rlb = wr * 64 + (lane >> 4) * 4;
    const int clb = wc * 64 + (lane & 15);

    if (MODE == 0) {
        if (z < 2) {
#pragma unroll
            for (int m = 0; m < 4; ++m)
#pragma unroll
                for (int n = 0; n < 4; ++n)
#pragma unroll
                    for (int j = 0; j < 4; ++j)
                        Cs[(rlb + m * 16 + j) * CP + clb + n * 16] = (__bf16)acc[m][n][j];
            __syncthreads();

            bf16_t* dst = (z == 0) ? outQ : outK;
            const int dch = t & 7;
            const int srow = t >> 3;
            float fr[4];
#pragma unroll
            for (int i = 0; i < 4; ++i)
                fr[i] = exp2f((float)(dch * 4 + i) * -0.4152410118609203f);
#pragma unroll
            for (int p = 0; p < 4; ++p) {
                const int s_loc = p * 32 + srow;
                const int gm = m0 + s_loc;
                const int bb = gm >> 11, sg = gm & (S_DIM - 1);
                const float pv = (float)pos[sg];
                float csv[4], snv[4];
#pragma unroll
                for (int i = 0; i < 4; ++i) {
                    const float a = pv * fr[i];
                    csv[i] = cosf(a); snv[i] = sinf(a);
                }
#pragma unroll
                for (int hc = 0; hc < 2; ++hc) {
                    const bf16x8 vv = *reinterpret_cast<const bf16x8*>(
                        &Cs[s_loc * CP + hc * 64 + dch * 8]);
                    bf16x8 ov;
#pragma unroll
                    for (int i = 0; i < 4; ++i) {
                        const float v0 = (float)vv[2 * i], v1 = (float)vv[2 * i + 1];
                        ov[2 * i]     = (__bf16)(v0 * csv[i] - v1 * snv[i]);
                        ov[2 * i + 1] = (__bf16)(v0 * snv[i] + v1 * csv[i]);
                    }
                    const int h = (n0 >> 6) + hc;
                    *reinterpret_cast<bf16x8*>(
                        &dst[((size_t)(bb * H_DIM + h) * S_DIM + sg) * 64 + dch * 8]) = ov;
                }
            }
        } else {
#pragma unroll
            for (int m = 0; m < 4; ++m)
#pragma unroll
                for (int n = 0; n < 4; ++n) {
                    const int cl = clb + n * 16;
                    bf16x4 v4;
#pragma unroll
                    for (int j = 0; j < 4; ++j) v4[j] = (__bf16)acc[m][n][j];
                    *reinterpret_cast<bf16x4*>(&Cs[cl * CP + rlb + m * 16]) = v4;
                }
            __syncthreads();

            const int cl = t >> 1, sh = t & 1;
            const int cg = n0 + cl, h = cg >> 6, d = cg & 63;
            const int bb = m0 >> 11, s0g = m0 & (S_DIM - 1);
            bf16_t* vdst = &outVt[((size_t)(bb * H_DIM + h) * DK + d) * S_DIM + s0g + sh * 64];
#pragma unroll
            for (int i = 0; i < 8; ++i)
                *reinterpret_cast<bf16x8*>(&vdst[i * 8]) =
                    *reinterpret_cast<const bf16x8*>(&Cs[cl * CP + sh * 64 + i * 8]);
        }
    } else {
        const int rbase = m0 + rlb;
        const int cbase = n0 + clb;
#pragma unroll
        for (int m = 0; m < 4; ++m)
#pragma unroll
            for (int n = 0; n < 4; ++n)
#pragma unroll
                for (int j = 0; j < 4; ++j)
                    outF[(size_t)(rbase + m * 16 + j) * DM + cbase + n * 16] = acc[m][n][j];
    }
}

// ---------------- causal flash attention v13: 8-wave 128-row strips ----------------
// Block = 8 waves (512 thr) = one 128-row q-strip (qB in 0..15, longest first);
// wave w owns rows q0 = qB*128 + w*16. K/V dbuf shared by 8 waves -> LDS/wave
// halves: 48 KB total -> 3 blocks/CU x 8 waves = 24 waves/CU ceiling (+50% TLP
// vs R15's 16). Per-tile math identical to proven v11; lower-half waves guard-
// idle exactly 1 tile at the end.
__global__ __launch_bounds__(512, 3)
void attn_kernel(const bf16_t* __restrict__ Q, const bf16_t* __restrict__ Kg,
                 const bf16_t* __restrict__ Vt, bf16_t* __restrict__ O) {
    __shared__ bf16_t Ks[2][64 * 64];
    __shared__ bf16_t Vs[2][64 * 64];
    __shared__ bf16_t P_lds[8][16 * 64];

    const int t = threadIdx.x;
    const int lane = t & 63;
    const int w = t >> 6;                  // 0..7
    const int qBo = blockIdx.x >> 5;       // 0..15, longest first
    const int qB = 15 - qBo;
    const int bh = blockIdx.x & 31;
    const int q0 = qB * 128 + w * 16;
    const int qbw = q0 >> 6;               // this wave's diagonal 64-tile
    const int b = bh >> 4, h = bh & 15;
    const int rr = lane & 15;
    const int hi = lane >> 4;
    const int psw = (rr & 7) * 8;          // P col XOR swizzle

    const bf16_t* Kbh = Kg + (size_t)bh * S_DIM * DK;
    const bf16_t* Vbh = Vt + (size_t)bh * DK * S_DIM;   // [d][s]
    bf16_t* Pw = P_lds[w];

    // staging: 512 x 16B chunks per 8KB tile; 512 threads -> 1 chunk each.
    // LDS dest linear; global source pre-swizzled: col ^= (row&7)*8 elems.
    const int r0 = t >> 3, c0 = ((t & 7) ^ (r0 & 7)) * 8;

    // Q fragments, folded scale = (1/8) * log2(e)
    const float QSCALE = 0.18033688011112042f;
    const bf16_t* Qp = Q + ((size_t)bh * S_DIM + q0) * DK;
    bf16x8 qf[2];
    qf[0] = *reinterpret_cast<const bf16x8*>(&Qp[rr * DK + hi * 8]);
    qf[1] = *reinterpret_cast<const bf16x8*>(&Qp[rr * DK + 32 + hi * 8]);
#pragma unroll
    for (int i = 0; i < 8; ++i) {
        qf[0][i] = (__bf16)((float)qf[0][i] * QSCALE);
        qf[1][i] = (__bf16)((float)qf[1][i] * QSCALE);
    }

    bf16x8 ones;
#pragma unroll
    for (int i = 0; i < 8; ++i) ones[i] = (__bf16)1.0f;

    f32x4 o[4] = {};
    f32x4 la = {};
    float m = -INFINITY;

    const int nt = 2 * qB + 2;             // kv tiles for the strip's top wave

    gload_lds16(Kbh + (size_t)r0 * DK + c0, &Ks[0][t * 8]);
    gload_lds16(Vbh + (size_t)r0 * S_DIM + c0, &Vs[0][t * 8]);
    __syncthreads();

    for (int tt = 0; tt < nt; ++tt) {
        const int cur = tt & 1;
        const int kv0 = tt * 64;

        if (tt + 1 < nt) {
            const int kv1 = kv0 + 64;
            gload_lds16(Kbh + (size_t)(kv1 + r0) * DK + c0, &Ks[cur ^ 1][t * 8]);
            gload_lds16(Vbh + (size_t)r0 * S_DIM + kv1 + c0, &Vs[cur ^ 1][t * 8]);
        }
        const bf16_t* Kc = Ks[cur];
        const bf16_t* Vc = Vs[cur];

        if (tt <= qbw) {
            // QK^T: s[t16][j] = S[kv = t16*16 + hi*4 + j][q = rr]
            f32x4 s[4] = {};
            __builtin_amdgcn_s_setprio(1);
#pragma unroll
            for (int t16 = 0; t16 < 4; ++t16) {
                const int r = t16 * 16 + rr;
                const int sw = (r & 7) * 8;
                bf16x8 kf0 = *reinterpret_cast<const bf16x8*>(&Kc[r * 64 + ((hi * 8) ^ sw)]);
                bf16x8 kf1 = *reinterpret_cast<const bf16x8*>(&Kc[r * 64 + ((32 + hi * 8) ^ sw)]);
                s[t16] = MFMA(kf0, qf[0], s[t16]);
                s[t16] = MFMA(kf1, qf[1], s[t16]);
            }
            __builtin_amdgcn_s_setprio(0);

            if (tt == qbw) {
                const int qg = q0 + rr;
#pragma unroll
                for (int t16 = 0; t16 < 4; ++t16)
#pragma unroll
                    for (int j = 0; j < 4; ++j)
                        if (kv0 + t16 * 16 + hi * 4 + j > qg) s[t16][j] = -INFINITY;
            }

            // softmax (lane-local defer-max trip, THR=8; l via ones-MFMA)
            f32x4 mv = s[0];
#pragma unroll
            for (int t16 = 1; t16 < 4; ++t16) {
                mv[0] = fmaxf(mv[0], s[t16][0]); mv[1] = fmaxf(mv[1], s[t16][1]);
                mv[2] = fmaxf(mv[2], s[t16][2]); mv[3] = fmaxf(mv[3], s[t16][3]);
            }
            const float mloc = fmaxf(fmaxf(mv[0], mv[1]), fmaxf(mv[2], mv[3]));
            if (__any(mloc - m > 8.0f)) {
                float mf = fmaxf(mloc, __shfl_xor(mloc, 16));
                mf = fmaxf(mf, __shfl_xor(mf, 32));
                const float mnew = fmaxf(m, mf);
                const float scale = exp2f(m - mnew);
#pragma unroll
                for (int i = 0; i < 4; ++i) la[i] *= scale;
#pragma unroll
                for (int db = 0; db < 4; ++db)
#pragma unroll
                    for (int j = 0; j < 4; ++j) o[db][j] *= scale;
                m = mnew;
            }
#pragma unroll
            for (int t16 = 0; t16 < 4; ++t16) {
                bf16x4 pb;
#pragma unroll
                for (int j = 0; j < 4; ++j) pb[j] = (__bf16)exp2f(s[t16][j] - m);
                *reinterpret_cast<bf16x4*>(&Pw[rr * 64 + ((t16 * 16 + hi * 4) ^ psw)]) = pb;
            }

            bf16x8 pf0 = *reinterpret_cast<const bf16x8*>(&Pw[rr * 64 + ((hi * 8) ^ psw)]);
            bf16x8 pf1 = *reinterpret_cast<const bf16x8*>(&Pw[rr * 64 + ((32 + hi * 8) ^ psw)]);
            __builtin_amdgcn_s_setprio(1);
            la = MFMA(ones, pf0, la);
            la = MFMA(ones, pf1, la);
#pragma unroll
            for (int db = 0; db < 4; ++db) {
                const int vr = db * 16 + rr;
                const int sw = (vr & 7) * 8;
                bf16x8 vf0 = *reinterpret_cast<const bf16x8*>(&Vc[vr * 64 + ((hi * 8) ^ sw)]);
                bf16x8 vf1 = *reinterpret_cast<const bf16x8*>(&Vc[vr * 64 + ((32 + hi * 8) ^ sw)]);
                o[db] = MFMA(vf0, pf0, o[db]);
                o[db] = MFMA(vf1, pf1, o[db]);
            }
            __builtin_amdgcn_s_setprio(0);
        }

        __syncthreads();
    }

    const float linv = 1.0f / la[0];
#pragma unroll
    for (int db = 0; db < 4; ++db) {
        bf16x4 ov;
#pragma unroll
        for (int j = 0; j < 4; ++j) ov[j] = (__bf16)(o[db][j] * linv);
        *reinterpret_cast<bf16x4*>(
            &O[((size_t)(b * S_DIM + q0 + rr)) * DM + h * DK + db * 16 + hi * 4]) = ov;
    }
}

extern "C" void kernel_launch(void* const* d_in, const int* in_sizes, int n_in,
                              void* d_out, int out_size, void* d_ws, size_t ws_size,
                              hipStream_t stream) {
    const float* x  = (const float*)d_in[0];
    const float* Wq = (const float*)d_in[1];
    const float* Wk = (const float*)d_in[2];
    const float* Wv = (const float*)d_in[3];
    const float* Wo = (const float*)d_in[4];
    const int* pos  = (const int*)d_in[5];
    float* out = (float*)d_out;

    char* ws = (char*)d_ws;
    bf16_t* xb  = (bf16_t*)(ws);
    bf16_t* Wqb = (bf16_t*)(ws + (8u << 20));
    bf16_t* Wkb = (bf16_t*)(ws + (10u << 20));
    bf16_t* Wvb = (bf16_t*)(ws + (12u << 20));
    bf16_t* Wob = (bf16_t*)(ws + (14u << 20));
    bf16_t* Qb  = (bf16_t*)(ws + (16u << 20));
    bf16_t* Kb  = (bf16_t*)(ws + (24u << 20));
    bf16_t* Vtb = (bf16_t*)(ws + (32u << 20));
    bf16_t* Ab  = (bf16_t*)(ws);  // reuse xb region after QKV GEMM

    const int NX = B_DIM * S_DIM * DM;
    const int NW = DM * DM;
    const int NTOT = NX + 4 * NW;  // 8388608

    cvt_all<<<NTOT / 1024, 256, 0, stream>>>(x, Wq, Wk, Wv, Wo,
                                             xb, Wqb, Wkb, Wvb, Wob);

    gemm_bt<0><<<dim3(32, 8, 3), 256, 0, stream>>>(xb, Wqb, Wkb, Wvb,
                                                   Qb, Kb, Vtb, nullptr, pos);

    attn_kernel<<<B_DIM * H_DIM * 16, 512, 0, stream>>>(Qb, Kb, Vtb, Ab);

    gemm_bt<1><<<dim3(32, 8, 1), 256, 0, stream>>>(Ab, Wob, nullptr, nullptr,
                                                   nullptr, nullptr, nullptr, out, pos);
}

// Round 19
// 115.531 us; speedup vs baseline: 1.0151x; 1.0151x over previous
//
#include <hip/hip_runtime.h>
#include <hip/hip_bf16.h>
#include <math.h>

typedef __bf16 bf16_t;
typedef __attribute__((ext_vector_type(8))) __bf16 bf16x8;
typedef __attribute__((ext_vector_type(4))) __bf16 bf16x4;
typedef __attribute__((ext_vector_type(4))) float f32x4;

#define B_DIM 2
#define S_DIM 2048
#define H_DIM 16
#define DK 64
#define DM 1024
#define KDIM 1024

#define MFMA(a, b, c) __builtin_amdgcn_mfma_f32_16x16x32_bf16((a), (b), (c), 0, 0, 0)

__device__ __forceinline__ void gload_lds16(const bf16_t* g, bf16_t* l) {
    __builtin_amdgcn_global_load_lds(
        (const __attribute__((address_space(1))) void*)g,
        (__attribute__((address_space(3))) void*)l, 16, 0, 0);
}

// ---------------- fp32 -> bf16 convert: x + 4 weights in ONE launch ----------------
__global__ void cvt_all(const float* __restrict__ x,
                        const float* __restrict__ wq, const float* __restrict__ wk,
                        const float* __restrict__ wv, const float* __restrict__ wo,
                        bf16_t* __restrict__ xb,
                        bf16_t* __restrict__ wqb, bf16_t* __restrict__ wkb,
                        bf16_t* __restrict__ wvb, bf16_t* __restrict__ wob) {
    const long NX = (long)B_DIM * S_DIM * DM;       // 4194304
    const long i = ((long)blockIdx.x * 256 + threadIdx.x) * 4;
    const float* s; bf16_t* d; long off;
    if (i < NX) { s = x; d = xb; off = i; }
    else {
        const long j = i - NX;
        const int wsel = (int)(j >> 20);            // NW = 1<<20
        off = j & ((1L << 20) - 1);
        switch (wsel) {
            case 0: s = wq; d = wqb; break;
            case 1: s = wk; d = wkb; break;
            case 2: s = wv; d = wvb; break;
            default: s = wo; d = wob; break;
        }
    }
    float4 v = *reinterpret_cast<const float4*>(s + off);
    bf16x4 o;
    o[0] = (__bf16)v.x; o[1] = (__bf16)v.y; o[2] = (__bf16)v.z; o[3] = (__bf16)v.w;
    *reinterpret_cast<bf16x4*>(d + off) = o;
}

// ---------------- GEMM: Y[m,n] = sum_k A[m,k] * B[n,k]  (B^T layout) ----------------
// K-loop: catalog T3-minimum (R9-proven structure): LDS double-buffered BK=32;
//   prologue STAGE(0); vmcnt(0); barrier
//   per iter: STAGE(t+1, buf^1) -> read frags + MFMA from buf -> vmcnt(0); barrier
// Buffer bases computed by offset arithmetic (no LDS pointer arrays — compiler
// rejects static addrspacecast initializers).
template <int MODE>
__global__ __launch_bounds__(256)
void gemm_bt(const bf16_t* __restrict__ A,
             const bf16_t* __restrict__ B0,
             const bf16_t* __restrict__ B1,
             const bf16_t* __restrict__ B2,
             bf16_t* __restrict__ outQ,
             bf16_t* __restrict__ outK,
             bf16_t* __restrict__ outVt,
             float* __restrict__ outF,
             const int* __restrict__ pos) {
    constexpr int CP = 136;
    constexpr int SELEMS = (MODE == 0) ? (128 * CP) : 16384;
    __shared__ bf16_t smem[SELEMS];
    // layout: [buf0: As 4096 | Bs 4096][buf1: As 4096 | Bs 4096]; Cs overlays all
    bf16_t* Cs = smem;

    const int t = threadIdx.x;
    const int z = blockIdx.z;
    const bf16_t* Bm = (MODE == 0) ? (z == 0 ? B0 : (z == 1 ? B1 : B2)) : B0;

    const int m0 = blockIdx.x * 128;
    const int n0 = blockIdx.y * 128;
    const int lane = t & 63;
    const int w = t >> 6;
    const int wr = w >> 1;
    const int wc = w & 1;

    f32x4 acc[4][4] = {};

    const int ar = t >> 2;         // staging row (0..63)
    const int ac = (t & 3) * 8;    // staging col (0,8,16,24)
    const bf16_t* Ag = A + (size_t)m0 * KDIM;
    const bf16_t* Bg = Bm + (size_t)n0 * KDIM;

    const int rr = lane & 15;
    const int ko = (lane >> 4) * 8;

    constexpr int NT = KDIM / 32;  // 32

    // prologue: stage tile 0 into buf 0, drain, barrier
    gload_lds16(Ag + (size_t)ar * KDIM + ac,        &smem[t * 8]);
    gload_lds16(Ag + (size_t)(ar + 64) * KDIM + ac, &smem[2048 + t * 8]);
    gload_lds16(Bg + (size_t)ar * KDIM + ac,        &smem[4096 + t * 8]);
    gload_lds16(Bg + (size_t)(ar + 64) * KDIM + ac, &smem[6144 + t * 8]);
    asm volatile("s_waitcnt vmcnt(0)" ::: "memory");
    __builtin_amdgcn_s_barrier();
    __builtin_amdgcn_sched_barrier(0);

    for (int it = 0; it < NT; ++it) {
        const int curo = (it & 1) * 8192;
        if (it + 1 < NT) {
            const int nxto = ((it + 1) & 1) * 8192;
            const int k1 = (it + 1) * 32;
            gload_lds16(Ag + (size_t)ar * KDIM + k1 + ac,        &smem[nxto + t * 8]);
            gload_lds16(Ag + (size_t)(ar + 64) * KDIM + k1 + ac, &smem[nxto + 2048 + t * 8]);
            gload_lds16(Bg + (size_t)ar * KDIM + k1 + ac,        &smem[nxto + 4096 + t * 8]);
            gload_lds16(Bg + (size_t)(ar + 64) * KDIM + k1 + ac, &smem[nxto + 6144 + t * 8]);
        }

        const bf16_t* Asc = smem + curo;
        const bf16_t* Bsc = smem + curo + 4096;
        bf16x8 af[4], bfr[4];
#pragma unroll
        for (int m = 0; m < 4; ++m)
            af[m] = *reinterpret_cast<const bf16x8*>(&Asc[(wr * 64 + m * 16 + rr) * 32 + ko]);
#pragma unroll
        for (int n = 0; n < 4; ++n)
            bfr[n] = *reinterpret_cast<const bf16x8*>(&Bsc[(wc * 64 + n * 16 + rr) * 32 + ko]);
        __builtin_amdgcn_s_setprio(1);
#pragma unroll
        for (int m = 0; m < 4; ++m)
#pragma unroll
            for (int n = 0; n < 4; ++n)
                acc[m][n] = MFMA(af[m], bfr[n], acc[m][n]);
        __builtin_amdgcn_s_setprio(0);

        asm volatile("s_waitcnt vmcnt(0)" ::: "memory");
        __builtin_amdgcn_s_barrier();
        __builtin_amdgcn_sched_barrier(0);
    }

    const int rlb = wr * 64 + (lane >> 4) * 4;
    const int clb = wc * 64 + (lane & 15);

    if (MODE == 0) {
        if (z < 2) {
#pragma unroll
            for (int m = 0; m < 4; ++m)
#pragma unroll
                for (int n = 0; n < 4; ++n)
#pragma unroll
                    for (int j = 0; j < 4; ++j)
                        Cs[(rlb + m * 16 + j) * CP + clb + n * 16] = (__bf16)acc[m][n][j];
            __syncthreads();

            bf16_t* dst = (z == 0) ? outQ : outK;
            const int dch = t & 7;
            const int srow = t >> 3;
            float fr[4];
#pragma unroll
            for (int i = 0; i < 4; ++i)
                fr[i] = exp2f((float)(dch * 4 + i) * -0.4152410118609203f);
#pragma unroll
            for (int p = 0; p < 4; ++p) {
                const int s_loc = p * 32 + srow;
                const int gm = m0 + s_loc;
                const int bb = gm >> 11, sg = gm & (S_DIM - 1);
                const float pv = (float)pos[sg];
                float csv[4], snv[4];
#pragma unroll
                for (int i = 0; i < 4; ++i) {
                    const float a = pv * fr[i];
                    csv[i] = cosf(a); snv[i] = sinf(a);
                }
#pragma unroll
                for (int hc = 0; hc < 2; ++hc) {
                    const bf16x8 vv = *reinterpret_cast<const bf16x8*>(
                        &Cs[s_loc * CP + hc * 64 + dch * 8]);
                    bf16x8 ov;
#pragma unroll
                    for (int i = 0; i < 4; ++i) {
                        const float v0 = (float)vv[2 * i], v1 = (float)vv[2 * i + 1];
                        ov[2 * i]     = (__bf16)(v0 * csv[i] - v1 * snv[i]);
                        ov[2 * i + 1] = (__bf16)(v0 * snv[i] + v1 * csv[i]);
                    }
                    const int h = (n0 >> 6) + hc;
                    *reinterpret_cast<bf16x8*>(
                        &dst[((size_t)(bb * H_DIM + h) * S_DIM + sg) * 64 + dch * 8]) = ov;
                }
            }
        } else {
#pragma unroll
            for (int m = 0; m < 4; ++m)
#pragma unroll
                for (int n = 0; n < 4; ++n) {
                    const int cl = clb + n * 16;
                    bf16x4 v4;
#pragma unroll
                    for (int j = 0; j < 4; ++j) v4[j] = (__bf16)acc[m][n][j];
                    *reinterpret_cast<bf16x4*>(&Cs[cl * CP + rlb + m * 16]) = v4;
                }
            __syncthreads();

            const int cl = t >> 1, sh = t & 1;
            const int cg = n0 + cl, h = cg >> 6, d = cg & 63;
            const int bb = m0 >> 11, s0g = m0 & (S_DIM - 1);
            bf16_t* vdst = &outVt[((size_t)(bb * H_DIM + h) * DK + d) * S_DIM + s0g + sh * 64];
#pragma unroll
            for (int i = 0; i < 8; ++i)
                *reinterpret_cast<bf16x8*>(&vdst[i * 8]) =
                    *reinterpret_cast<const bf16x8*>(&Cs[cl * CP + sh * 64 + i * 8]);
        }
    } else {
        const int rbase = m0 + rlb;
        const int cbase = n0 + clb;
#pragma unroll
        for (int m = 0; m < 4; ++m)
#pragma unroll
            for (int n = 0; n < 4; ++n)
#pragma unroll
                for (int j = 0; j < 4; ++j)
                    outF[(size_t)(rbase + m * 16 + j) * DM + cbase + n * 16] = acc[m][n][j];
    }
}

// ---------------- causal flash attention v11 (R15-exact, proven 46.4 us) ----------
__global__ __launch_bounds__(256, 4)
void attn_kernel(const bf16_t* __restrict__ Q, const bf16_t* __restrict__ Kg,
                 const bf16_t* __restrict__ Vt, bf16_t* __restrict__ O) {
    __shared__ bf16_t Ks[2][64 * 64];
    __shared__ bf16_t Vs[2][64 * 64];
    __shared__ bf16_t P_lds[4][16 * 64];

    const int t = threadIdx.x;
    const int lane = t & 63;
    const int w = t >> 6;                  // 0..3
    const int qbo = blockIdx.x >> 5;       // 0..31 (longest first)
    const int qb = 31 - qbo;
    const int bh = blockIdx.x & 31;
    const int q0 = qb * 64 + w * 16;
    const int b = bh >> 4, h = bh & 15;
    const int rr = lane & 15;
    const int hi = lane >> 4;
    const int psw = (rr & 7) * 8;          // P col XOR swizzle

    const bf16_t* Kbh = Kg + (size_t)bh * S_DIM * DK;
    const bf16_t* Vbh = Vt + (size_t)bh * DK * S_DIM;   // [d][s]
    bf16_t* Pw = P_lds[w];

    const int i0 = t, i1 = t + 256;
    const int r0 = i0 >> 3, c0 = ((i0 & 7) ^ (r0 & 7)) * 8;
    const int r1 = i1 >> 3, c1 = ((i1 & 7) ^ (r1 & 7)) * 8;

    // Q fragments, folded scale = (1/8) * log2(e)
    const float QSCALE = 0.18033688011112042f;
    const bf16_t* Qp = Q + ((size_t)bh * S_DIM + q0) * DK;
    bf16x8 qf[2];
    qf[0] = *reinterpret_cast<const bf16x8*>(&Qp[rr * DK + hi * 8]);
    qf[1] = *reinterpret_cast<const bf16x8*>(&Qp[rr * DK + 32 + hi * 8]);
#pragma unroll
    for (int i = 0; i < 8; ++i) {
        qf[0][i] = (__bf16)((float)qf[0][i] * QSCALE);
        qf[1][i] = (__bf16)((float)qf[1][i] * QSCALE);
    }

    bf16x8 ones;
#pragma unroll
    for (int i = 0; i < 8; ++i) ones[i] = (__bf16)1.0f;

    f32x4 o[4] = {};
    f32x4 la = {};
    float m = -INFINITY;

    const int nt = qb + 1;

    gload_lds16(Kbh + (size_t)r0 * DK + c0, &Ks[0][i0 * 8]);
    gload_lds16(Kbh + (size_t)r1 * DK + c1, &Ks[0][i1 * 8]);
    gload_lds16(Vbh + (size_t)r0 * S_DIM + c0, &Vs[0][i0 * 8]);
    gload_lds16(Vbh + (size_t)r1 * S_DIM + c1, &Vs[0][i1 * 8]);
    __syncthreads();

    for (int tt = 0; tt < nt; ++tt) {
        const int cur = tt & 1;
        const int kv0 = tt * 64;

        if (tt + 1 < nt) {
            const int kv1 = kv0 + 64;
            bf16_t* Kn = Ks[cur ^ 1];
            bf16_t* Vn = Vs[cur ^ 1];
            gload_lds16(Kbh + (size_t)(kv1 + r0) * DK + c0, &Kn[i0 * 8]);
            gload_lds16(Kbh + (size_t)(kv1 + r1) * DK + c1, &Kn[i1 * 8]);
            gload_lds16(Vbh + (size_t)r0 * S_DIM + kv1 + c0, &Vn[i0 * 8]);
            gload_lds16(Vbh + (size_t)r1 * S_DIM + kv1 + c1, &Vn[i1 * 8]);
        }
        const bf16_t* Kc = Ks[cur];
        const bf16_t* Vc = Vs[cur];

        // QK^T: s[t16][j] = S[kv = t16*16 + hi*4 + j][q = rr]
        f32x4 s[4] = {};
        __builtin_amdgcn_s_setprio(1);
#pragma unroll
        for (int t16 = 0; t16 < 4; ++t16) {
            const int r = t16 * 16 + rr;
            const int sw = (r & 7) * 8;
            bf16x8 kf0 = *reinterpret_cast<const bf16x8*>(&Kc[r * 64 + ((hi * 8) ^ sw)]);
            bf16x8 kf1 = *reinterpret_cast<const bf16x8*>(&Kc[r * 64 + ((32 + hi * 8) ^ sw)]);
            s[t16] = MFMA(kf0, qf[0], s[t16]);
            s[t16] = MFMA(kf1, qf[1], s[t16]);
        }
        __builtin_amdgcn_s_setprio(0);

        if (tt == qb) {
            const int qg = q0 + rr;
#pragma unroll
            for (int t16 = 0; t16 < 4; ++t16)
#pragma unroll
                for (int j = 0; j < 4; ++j)
                    if (kv0 + t16 * 16 + hi * 4 + j > qg) s[t16][j] = -INFINITY;
        }

        // softmax (lane-local defer-max trip, THR=8; l via ones-MFMA)
        f32x4 mv = s[0];
#pragma unroll
        for (int t16 = 1; t16 < 4; ++t16) {
            mv[0] = fmaxf(mv[0], s[t16][0]); mv[1] = fmaxf(mv[1], s[t16][1]);
            mv[2] = fmaxf(mv[2], s[t16][2]); mv[3] = fmaxf(mv[3], s[t16][3]);
        }
        const float mloc = fmaxf(fmaxf(mv[0], mv[1]), fmaxf(mv[2], mv[3]));
        if (__any(mloc - m > 8.0f)) {
            float mf = fmaxf(mloc, __shfl_xor(mloc, 16));
            mf = fmaxf(mf, __shfl_xor(mf, 32));
            const float mnew = fmaxf(m, mf);
            const float scale = exp2f(m - mnew);
#pragma unroll
            for (int i = 0; i < 4; ++i) la[i] *= scale;
#pragma unroll
            for (int db = 0; db < 4; ++db)
#pragma unroll
                for (int j = 0; j < 4; ++j) o[db][j] *= scale;
            m = mnew;
        }
#pragma unroll
        for (int t16 = 0; t16 < 4; ++t16) {
            bf16x4 pb;
#pragma unroll
            for (int j = 0; j < 4; ++j) pb[j] = (__bf16)exp2f(s[t16][j] - m);
            *reinterpret_cast<bf16x4*>(&Pw[rr * 64 + ((t16 * 16 + hi * 4) ^ psw)]) = pb;
        }

        bf16x8 pf0 = *reinterpret_cast<const bf16x8*>(&Pw[rr * 64 + ((hi * 8) ^ psw)]);
        bf16x8 pf1 = *reinterpret_cast<const bf16x8*>(&Pw[rr * 64 + ((32 + hi * 8) ^ psw)]);
        __builtin_amdgcn_s_setprio(1);
        la = MFMA(ones, pf0, la);
        la = MFMA(ones, pf1, la);
#pragma unroll
        for (int db = 0; db < 4; ++db) {
            const int vr = db * 16 + rr;
            const int sw = (vr & 7) * 8;
            bf16x8 vf0 = *reinterpret_cast<const bf16x8*>(&Vc[vr * 64 + ((hi * 8) ^ sw)]);
            bf16x8 vf1 = *reinterpret_cast<const bf16x8*>(&Vc[vr * 64 + ((32 + hi * 8) ^ sw)]);
            o[db] = MFMA(vf0, pf0, o[db]);
            o[db] = MFMA(vf1, pf1, o[db]);
        }
        __builtin_amdgcn_s_setprio(0);

        __syncthreads();
    }

    const float linv = 1.0f / la[0];
#pragma unroll
    for (int db = 0; db < 4; ++db) {
        bf16x4 ov;
#pragma unroll
        for (int j = 0; j < 4; ++j) ov[j] = (__bf16)(o[db][j] * linv);
        *reinterpret_cast<bf16x4*>(
            &O[((size_t)(b * S_DIM + q0 + rr)) * DM + h * DK + db * 16 + hi * 4]) = ov;
    }
}

extern "C" void kernel_launch(void* const* d_in, const int* in_sizes, int n_in,
                              void* d_out, int out_size, void* d_ws, size_t ws_size,
                              hipStream_t stream) {
    const float* x  = (const float*)d_in[0];
    const float* Wq = (const float*)d_in[1];
    const float* Wk = (const float*)d_in[2];
    const float* Wv = (const float*)d_in[3];
    const float* Wo = (const float*)d_in[4];
    const int* pos  = (const int*)d_in[5];
    float* out = (float*)d_out;

    char* ws = (char*)d_ws;
    bf16_t* xb  = (bf16_t*)(ws);
    bf16_t* Wqb = (bf16_t*)(ws + (8u << 20));
    bf16_t* Wkb = (bf16_t*)(ws + (10u << 20));
    bf16_t* Wvb = (bf16_t*)(ws + (12u << 20));
    bf16_t* Wob = (bf16_t*)(ws + (14u << 20));
    bf16_t* Qb  = (bf16_t*)(ws + (16u << 20));
    bf16_t* Kb  = (bf16_t*)(ws + (24u << 20));
    bf16_t* Vtb = (bf16_t*)(ws + (32u << 20));
    bf16_t* Ab  = (bf16_t*)(ws);  // reuse xb region after QKV GEMM

    const int NX = B_DIM * S_DIM * DM;
    const int NW = DM * DM;
    const int NTOT = NX + 4 * NW;  // 8388608

    cvt_all<<<NTOT / 1024, 256, 0, stream>>>(x, Wq, Wk, Wv, Wo,
                                             xb, Wqb, Wkb, Wvb, Wob);

    gemm_bt<0><<<dim3(32, 8, 3), 256, 0, stream>>>(xb, Wqb, Wkb, Wvb,
                                                   Qb, Kb, Vtb, nullptr, pos);

    attn_kernel<<<B_DIM * H_DIM * 32, 256, 0, stream>>>(Qb, Kb, Vtb, Ab);

    gemm_bt<1><<<dim3(32, 8, 1), 256, 0, stream>>>(Ab, Wob, nullptr, nullptr,
                                                   nullptr, nullptr, nullptr, out, pos);
}

// Round 20
// 112.108 us; speedup vs baseline: 1.0461x; 1.0305x over previous
//
#include <hip/hip_runtime.h>
#include <hip/hip_bf16.h>
#include <math.h>

typedef __bf16 bf16_t;
typedef __attribute__((ext_vector_type(8))) __bf16 bf16x8;
typedef __attribute__((ext_vector_type(4))) __bf16 bf16x4;
typedef __attribute__((ext_vector_type(4))) float f32x4;

#define B_DIM 2
#define S_DIM 2048
#define H_DIM 16
#define DK 64
#define DM 1024
#define KDIM 1024

#define MFMA(a, b, c) __builtin_amdgcn_mfma_f32_16x16x32_bf16((a), (b), (c), 0, 0, 0)

__device__ __forceinline__ void gload_lds16(const bf16_t* g, bf16_t* l) {
    __builtin_amdgcn_global_load_lds(
        (const __attribute__((address_space(1))) void*)g,
        (__attribute__((address_space(3))) void*)l, 16, 0, 0);
}

// ---------------- fp32 -> bf16 convert: x + 4 weights in ONE launch ----------------
__global__ void cvt_all(const float* __restrict__ x,
                        const float* __restrict__ wq, const float* __restrict__ wk,
                        const float* __restrict__ wv, const float* __restrict__ wo,
                        bf16_t* __restrict__ xb,
                        bf16_t* __restrict__ wqb, bf16_t* __restrict__ wkb,
                        bf16_t* __restrict__ wvb, bf16_t* __restrict__ wob) {
    const long NX = (long)B_DIM * S_DIM * DM;       // 4194304
    const long i = ((long)blockIdx.x * 256 + threadIdx.x) * 4;
    const float* s; bf16_t* d; long off;
    if (i < NX) { s = x; d = xb; off = i; }
    else {
        const long j = i - NX;
        const int wsel = (int)(j >> 20);            // NW = 1<<20
        off = j & ((1L << 20) - 1);
        switch (wsel) {
            case 0: s = wq; d = wqb; break;
            case 1: s = wk; d = wkb; break;
            case 2: s = wv; d = wvb; break;
            default: s = wo; d = wob; break;
        }
    }
    float4 v = *reinterpret_cast<const float4*>(s + off);
    bf16x4 o;
    o[0] = (__bf16)v.x; o[1] = (__bf16)v.y; o[2] = (__bf16)v.z; o[3] = (__bf16)v.w;
    *reinterpret_cast<bf16x4*>(d + off) = o;
}

// ---------------- GEMM: Y[m,n] = sum_k A[m,k] * B[n,k]  (B^T layout) ----------------
// R12-proven BK=64 XOR-swizzled 2-sync K-loop + coalesced epilogues, plus
// T1 XCD-aware block swizzle: per z-slice, flat = x + 32*y remapped via
// swz = (flat&7)*32 + (flat>>3)  (bijective, 256%8==0) so each XCD keeps ONE
// B-panel L2-resident instead of round-robining across all 8.
template <int MODE>
__global__ __launch_bounds__(256)
void gemm_bt(const bf16_t* __restrict__ A,
             const bf16_t* __restrict__ B0,
             const bf16_t* __restrict__ B1,
             const bf16_t* __restrict__ B2,
             bf16_t* __restrict__ outQ,
             bf16_t* __restrict__ outK,
             bf16_t* __restrict__ outVt,
             float* __restrict__ outF,
             const int* __restrict__ pos) {
    constexpr int CP = 136;
    constexpr int SELEMS = (MODE == 0) ? (128 * CP) : 16384;
    __shared__ bf16_t smem[SELEMS];
    bf16_t* As = smem;            // [128][64] swizzled
    bf16_t* Bs = smem + 8192;     // [128][64] swizzled
    bf16_t* Cs = smem;            // epilogue overlay

    const int t = threadIdx.x;
    const int z = blockIdx.z;
    const bf16_t* Bm = (MODE == 0) ? (z == 0 ? B0 : (z == 1 ? B1 : B2)) : B0;

    // T1 XCD swizzle (bijective): each XCD gets one full x-column per y-panel
    const int flat = blockIdx.x + 32 * blockIdx.y;
    const int swz = (flat & 7) * 32 + (flat >> 3);
    const int m0 = (swz & 31) * 128;
    const int n0 = (swz >> 5) * 128;

    const int lane = t & 63;
    const int w = t >> 6;
    const int wr = w >> 1;
    const int wc = w & 1;

    f32x4 acc[4][4] = {};

    const bf16_t* Ag = A + (size_t)m0 * KDIM;
    const bf16_t* Bg = Bm + (size_t)n0 * KDIM;

    const int rr = lane & 15;
    const int ko = (lane >> 4) * 8;

    int rI[4], cI[4];
#pragma unroll
    for (int c = 0; c < 4; ++c) {
        const int i = t + c * 256;
        rI[c] = i >> 3;
        cI[c] = ((i & 7) ^ (rI[c] & 7)) * 8;
    }

    for (int k0 = 0; k0 < KDIM; k0 += 64) {
#pragma unroll
        for (int c = 0; c < 4; ++c) {
            const int i = t + c * 256;
            gload_lds16(Ag + (size_t)rI[c] * KDIM + k0 + cI[c], &As[i * 8]);
        }
#pragma unroll
        for (int c = 0; c < 4; ++c) {
            const int i = t + c * 256;
            gload_lds16(Bg + (size_t)rI[c] * KDIM + k0 + cI[c], &Bs[i * 8]);
        }
        __syncthreads();

        bf16x8 af[2][4], bfr[2][4];
#pragma unroll
        for (int kk = 0; kk < 2; ++kk) {
#pragma unroll
            for (int m = 0; m < 4; ++m) {
                const int r = wr * 64 + m * 16 + rr;
                af[kk][m] = *reinterpret_cast<const bf16x8*>(
                    &As[r * 64 + ((kk * 32 + ko) ^ ((r & 7) * 8))]);
            }
#pragma unroll
            for (int n = 0; n < 4; ++n) {
                const int r = wc * 64 + n * 16 + rr;
                bfr[kk][n] = *reinterpret_cast<const bf16x8*>(
                    &Bs[r * 64 + ((kk * 32 + ko) ^ ((r & 7) * 8))]);
            }
        }
        __builtin_amdgcn_s_setprio(1);
#pragma unroll
        for (int kk = 0; kk < 2; ++kk)
#pragma unroll
            for (int m = 0; m < 4; ++m)
#pragma unroll
                for (int n = 0; n < 4; ++n)
                    acc[m][n] = MFMA(af[kk][m], bfr[kk][n], acc[m][n]);
        __builtin_amdgcn_s_setprio(0);
        __syncthreads();
    }

    const int rlb = wr * 64 + (lane >> 4) * 4;
    const int clb = wc * 64 + (lane & 15);

    if (MODE == 0) {
        if (z < 2) {
#pragma unroll
            for (int m = 0; m < 4; ++m)
#pragma unroll
                for (int n = 0; n < 4; ++n)
#pragma unroll
                    for (int j = 0; j < 4; ++j)
                        Cs[(rlb + m * 16 + j) * CP + clb + n * 16] = (__bf16)acc[m][n][j];
            __syncthreads();

            bf16_t* dst = (z == 0) ? outQ : outK;
            const int dch = t & 7;
            const int srow = t >> 3;
            float fr[4];
#pragma unroll
            for (int i = 0; i < 4; ++i)
                fr[i] = exp2f((float)(dch * 4 + i) * -0.4152410118609203f);
#pragma unroll
            for (int p = 0; p < 4; ++p) {
                const int s_loc = p * 32 + srow;
                const int gm = m0 + s_loc;
                const int bb = gm >> 11, sg = gm & (S_DIM - 1);
                const float pv = (float)pos[sg];
                float csv[4], snv[4];
#pragma unroll
                for (int i = 0; i < 4; ++i) {
                    const float a = pv * fr[i];
                    csv[i] = cosf(a); snv[i] = sinf(a);
                }
#pragma unroll
                for (int hc = 0; hc < 2; ++hc) {
                    const bf16x8 vv = *reinterpret_cast<const bf16x8*>(
                        &Cs[s_loc * CP + hc * 64 + dch * 8]);
                    bf16x8 ov;
#pragma unroll
                    for (int i = 0; i < 4; ++i) {
                        const float v0 = (float)vv[2 * i], v1 = (float)vv[2 * i + 1];
                        ov[2 * i]     = (__bf16)(v0 * csv[i] - v1 * snv[i]);
                        ov[2 * i + 1] = (__bf16)(v0 * snv[i] + v1 * csv[i]);
                    }
                    const int h = (n0 >> 6) + hc;
                    *reinterpret_cast<bf16x8*>(
                        &dst[((size_t)(bb * H_DIM + h) * S_DIM + sg) * 64 + dch * 8]) = ov;
                }
            }
        } else {
#pragma unroll
            for (int m = 0; m < 4; ++m)
#pragma unroll
                for (int n = 0; n < 4; ++n) {
                    const int cl = clb + n * 16;
                    bf16x4 v4;
#pragma unroll
                    for (int j = 0; j < 4; ++j) v4[j] = (__bf16)acc[m][n][j];
                    *reinterpret_cast<bf16x4*>(&Cs[cl * CP + rlb + m * 16]) = v4;
                }
            __syncthreads();

            const int cl = t >> 1, sh = t & 1;
            const int cg = n0 + cl, h = cg >> 6, d = cg & 63;
            const int bb = m0 >> 11, s0g = m0 & (S_DIM - 1);
            bf16_t* vdst = &outVt[((size_t)(bb * H_DIM + h) * DK + d) * S_DIM + s0g + sh * 64];
#pragma unroll
            for (int i = 0; i < 8; ++i)
                *reinterpret_cast<bf16x8*>(&vdst[i * 8]) =
                    *reinterpret_cast<const bf16x8*>(&Cs[cl * CP + sh * 64 + i * 8]);
        }
    } else {
        const int rbase = m0 + rlb;
        const int cbase = n0 + clb;
#pragma unroll
        for (int m = 0; m < 4; ++m)
#pragma unroll
            for (int n = 0; n < 4; ++n)
#pragma unroll
                for (int j = 0; j < 4; ++j)
                    outF[(size_t)(rbase + m * 16 + j) * DM + cbase + n * 16] = acc[m][n][j];
    }
}

// ---------------- causal flash attention v11 (R15-exact, proven 46.4 us) ----------
__global__ __launch_bounds__(256, 4)
void attn_kernel(const bf16_t* __restrict__ Q, const bf16_t* __restrict__ Kg,
                 const bf16_t* __restrict__ Vt, bf16_t* __restrict__ O) {
    __shared__ bf16_t Ks[2][64 * 64];
    __shared__ bf16_t Vs[2][64 * 64];
    __shared__ bf16_t P_lds[4][16 * 64];

    const int t = threadIdx.x;
    const int lane = t & 63;
    const int w = t >> 6;                  // 0..3
    const int qbo = blockIdx.x >> 5;       // 0..31 (longest first)
    const int qb = 31 - qbo;
    const int bh = blockIdx.x & 31;
    const int q0 = qb * 64 + w * 16;
    const int b = bh >> 4, h = bh & 15;
    const int rr = lane & 15;
    const int hi = lane >> 4;
    const int psw = (rr & 7) * 8;          // P col XOR swizzle

    const bf16_t* Kbh = Kg + (size_t)bh * S_DIM * DK;
    const bf16_t* Vbh = Vt + (size_t)bh * DK * S_DIM;   // [d][s]
    bf16_t* Pw = P_lds[w];

    const int i0 = t, i1 = t + 256;
    const int r0 = i0 >> 3, c0 = ((i0 & 7) ^ (r0 & 7)) * 8;
    const int r1 = i1 >> 3, c1 = ((i1 & 7) ^ (r1 & 7)) * 8;

    // Q fragments, folded scale = (1/8) * log2(e)
    const float QSCALE = 0.18033688011112042f;
    const bf16_t* Qp = Q + ((size_t)bh * S_DIM + q0) * DK;
    bf16x8 qf[2];
    qf[0] = *reinterpret_cast<const bf16x8*>(&Qp[rr * DK + hi * 8]);
    qf[1] = *reinterpret_cast<const bf16x8*>(&Qp[rr * DK + 32 + hi * 8]);
#pragma unroll
    for (int i = 0; i < 8; ++i) {
        qf[0][i] = (__bf16)((float)qf[0][i] * QSCALE);
        qf[1][i] = (__bf16)((float)qf[1][i] * QSCALE);
    }

    bf16x8 ones;
#pragma unroll
    for (int i = 0; i < 8; ++i) ones[i] = (__bf16)1.0f;

    f32x4 o[4] = {};
    f32x4 la = {};
    float m = -INFINITY;

    const int nt = qb + 1;

    gload_lds16(Kbh + (size_t)r0 * DK + c0, &Ks[0][i0 * 8]);
    gload_lds16(Kbh + (size_t)r1 * DK + c1, &Ks[0][i1 * 8]);
    gload_lds16(Vbh + (size_t)r0 * S_DIM + c0, &Vs[0][i0 * 8]);
    gload_lds16(Vbh + (size_t)r1 * S_DIM + c1, &Vs[0][i1 * 8]);
    __syncthreads();

    for (int tt = 0; tt < nt; ++tt) {
        const int cur = tt & 1;
        const int kv0 = tt * 64;

        if (tt + 1 < nt) {
            const int kv1 = kv0 + 64;
            bf16_t* Kn = Ks[cur ^ 1];
            bf16_t* Vn = Vs[cur ^ 1];
            gload_lds16(Kbh + (size_t)(kv1 + r0) * DK + c0, &Kn[i0 * 8]);
            gload_lds16(Kbh + (size_t)(kv1 + r1) * DK + c1, &Kn[i1 * 8]);
            gload_lds16(Vbh + (size_t)r0 * S_DIM + kv1 + c0, &Vn[i0 * 8]);
            gload_lds16(Vbh + (size_t)r1 * S_DIM + kv1 + c1, &Vn[i1 * 8]);
        }
        const bf16_t* Kc = Ks[cur];
        const bf16_t* Vc = Vs[cur];

        // QK^T: s[t16][j] = S[kv = t16*16 + hi*4 + j][q = rr]
        f32x4 s[4] = {};
        __builtin_amdgcn_s_setprio(1);
#pragma unroll
        for (int t16 = 0; t16 < 4; ++t16) {
            const int r = t16 * 16 + rr;
            const int sw = (r & 7) * 8;
            bf16x8 kf0 = *reinterpret_cast<const bf16x8*>(&Kc[r * 64 + ((hi * 8) ^ sw)]);
            bf16x8 kf1 = *reinterpret_cast<const bf16x8*>(&Kc[r * 64 + ((32 + hi * 8) ^ sw)]);
            s[t16] = MFMA(kf0, qf[0], s[t16]);
            s[t16] = MFMA(kf1, qf[1], s[t16]);
        }
        __builtin_amdgcn_s_setprio(0);

        if (tt == qb) {
            const int qg = q0 + rr;
#pragma unroll
            for (int t16 = 0; t16 < 4; ++t16)
#pragma unroll
                for (int j = 0; j < 4; ++j)
                    if (kv0 + t16 * 16 + hi * 4 + j > qg) s[t16][j] = -INFINITY;
        }

        // softmax (lane-local defer-max trip, THR=8; l via ones-MFMA)
        f32x4 mv = s[0];
#pragma unroll
        for (int t16 = 1; t16 < 4; ++t16) {
            mv[0] = fmaxf(mv[0], s[t16][0]); mv[1] = fmaxf(mv[1], s[t16][1]);
            mv[2] = fmaxf(mv[2], s[t16][2]); mv[3] = fmaxf(mv[3], s[t16][3]);
        }
        const float mloc = fmaxf(fmaxf(mv[0], mv[1]), fmaxf(mv[2], mv[3]));
        if (__any(mloc - m > 8.0f)) {
            float mf = fmaxf(mloc, __shfl_xor(mloc, 16));
            mf = fmaxf(mf, __shfl_xor(mf, 32));
            const float mnew = fmaxf(m, mf);
            const float scale = exp2f(m - mnew);
#pragma unroll
            for (int i = 0; i < 4; ++i) la[i] *= scale;
#pragma unroll
            for (int db = 0; db < 4; ++db)
#pragma unroll
                for (int j = 0; j < 4; ++j) o[db][j] *= scale;
            m = mnew;
        }
#pragma unroll
        for (int t16 = 0; t16 < 4; ++t16) {
            bf16x4 pb;
#pragma unroll
            for (int j = 0; j < 4; ++j) pb[j] = (__bf16)exp2f(s[t16][j] - m);
            *reinterpret_cast<bf16x4*>(&Pw[rr * 64 + ((t16 * 16 + hi * 4) ^ psw)]) = pb;
        }

        bf16x8 pf0 = *reinterpret_cast<const bf16x8*>(&Pw[rr * 64 + ((hi * 8) ^ psw)]);
        bf16x8 pf1 = *reinterpret_cast<const bf16x8*>(&Pw[rr * 64 + ((32 + hi * 8) ^ psw)]);
        __builtin_amdgcn_s_setprio(1);
        la = MFMA(ones, pf0, la);
        la = MFMA(ones, pf1, la);
#pragma unroll
        for (int db = 0; db < 4; ++db) {
            const int vr = db * 16 + rr;
            const int sw = (vr & 7) * 8;
            bf16x8 vf0 = *reinterpret_cast<const bf16x8*>(&Vc[vr * 64 + ((hi * 8) ^ sw)]);
            bf16x8 vf1 = *reinterpret_cast<const bf16x8*>(&Vc[vr * 64 + ((32 + hi * 8) ^ sw)]);
            o[db] = MFMA(vf0, pf0, o[db]);
            o[db] = MFMA(vf1, pf1, o[db]);
        }
        __builtin_amdgcn_s_setprio(0);

        __syncthreads();
    }

    const float linv = 1.0f / la[0];
#pragma unroll
    for (int db = 0; db < 4; ++db) {
        bf16x4 ov;
#pragma unroll
        for (int j = 0; j < 4; ++j) ov[j] = (__bf16)(o[db][j] * linv);
        *reinterpret_cast<bf16x4*>(
            &O[((size_t)(b * S_DIM + q0 + rr)) * DM + h * DK + db * 16 + hi * 4]) = ov;
    }
}

extern "C" void kernel_launch(void* const* d_in, const int* in_sizes, int n_in,
                              void* d_out, int out_size, void* d_ws, size_t ws_size,
                              hipStream_t stream) {
    const float* x  = (const float*)d_in[0];
    const float* Wq = (const float*)d_in[1];
    const float* Wk = (const float*)d_in[2];
    const float* Wv = (const float*)d_in[3];
    const float* Wo = (const float*)d_in[4];
    const int* pos  = (const int*)d_in[5];
    float* out = (float*)d_out;

    char* ws = (char*)d_ws;
    bf16_t* xb  = (bf16_t*)(ws);
    bf16_t* Wqb = (bf16_t*)(ws + (8u << 20));
    bf16_t* Wkb = (bf16_t*)(ws + (10u << 20));
    bf16_t* Wvb = (bf16_t*)(ws + (12u << 20));
    bf16_t* Wob = (bf16_t*)(ws + (14u << 20));
    bf16_t* Qb  = (bf16_t*)(ws + (16u << 20));
    bf16_t* Kb  = (bf16_t*)(ws + (24u << 20));
    bf16_t* Vtb = (bf16_t*)(ws + (32u << 20));
    bf16_t* Ab  = (bf16_t*)(ws);  // reuse xb region after QKV GEMM

    const int NX = B_DIM * S_DIM * DM;
    const int NW = DM * DM;
    const int NTOT = NX + 4 * NW;  // 8388608

    cvt_all<<<NTOT / 1024, 256, 0, stream>>>(x, Wq, Wk, Wv, Wo,
                                             xb, Wqb, Wkb, Wvb, Wob);

    gemm_bt<0><<<dim3(32, 8, 3), 256, 0, stream>>>(xb, Wqb, Wkb, Wvb,
                                                   Qb, Kb, Vtb, nullptr, pos);

    attn_kernel<<<B_DIM * H_DIM * 32, 256, 0, stream>>>(Qb, Kb, Vtb, Ab);

    gemm_bt<1><<<dim3(32, 8, 1), 256, 0, stream>>>(Ab, Wob, nullptr, nullptr,
                                                   nullptr, nullptr, nullptr, out, pos);
}

// Round 21
// 110.080 us; speedup vs baseline: 1.0654x; 1.0184x over previous
//
#include <hip/hip_runtime.h>
#include <hip/hip_bf16.h>
#include <math.h>

typedef __bf16 bf16_t;
typedef __attribute__((ext_vector_type(8))) __bf16 bf16x8;
typedef __attribute__((ext_vector_type(4))) __bf16 bf16x4;
typedef __attribute__((ext_vector_type(4))) float f32x4;

#define B_DIM 2
#define S_DIM 2048
#define H_DIM 16
#define DK 64
#define DM 1024
#define KDIM 1024

#define MFMA(a, b, c) __builtin_amdgcn_mfma_f32_16x16x32_bf16((a), (b), (c), 0, 0, 0)

__device__ __forceinline__ void gload_lds16(const bf16_t* g, bf16_t* l) {
    __builtin_amdgcn_global_load_lds(
        (const __attribute__((address_space(1))) void*)g,
        (__attribute__((address_space(3))) void*)l, 16, 0, 0);
}

// ---------------- fp32 -> bf16 convert: x + 4 weights in ONE launch ----------------
__global__ void cvt_all(const float* __restrict__ x,
                        const float* __restrict__ wq, const float* __restrict__ wk,
                        const float* __restrict__ wv, const float* __restrict__ wo,
                        bf16_t* __restrict__ xb,
                        bf16_t* __restrict__ wqb, bf16_t* __restrict__ wkb,
                        bf16_t* __restrict__ wvb, bf16_t* __restrict__ wob) {
    const long NX = (long)B_DIM * S_DIM * DM;       // 4194304
    const long i = ((long)blockIdx.x * 256 + threadIdx.x) * 4;
    const float* s; bf16_t* d; long off;
    if (i < NX) { s = x; d = xb; off = i; }
    else {
        const long j = i - NX;
        const int wsel = (int)(j >> 20);            // NW = 1<<20
        off = j & ((1L << 20) - 1);
        switch (wsel) {
            case 0: s = wq; d = wqb; break;
            case 1: s = wk; d = wkb; break;
            case 2: s = wv; d = wvb; break;
            default: s = wo; d = wob; break;
        }
    }
    float4 v = *reinterpret_cast<const float4*>(s + off);
    bf16x4 o;
    o[0] = (__bf16)v.x; o[1] = (__bf16)v.y; o[2] = (__bf16)v.z; o[3] = (__bf16)v.w;
    *reinterpret_cast<bf16x4*>(d + off) = o;
}

// ---------------- GEMM: Y[m,n] = sum_k A[m,k] * B[n,k]  (B^T layout) ----------------
// (R12-proven: BK=64 XOR-swizzled 2-sync K-loop + coalesced epilogues)
template <int MODE>
__global__ __launch_bounds__(256)
void gemm_bt(const bf16_t* __restrict__ A,
             const bf16_t* __restrict__ B0,
             const bf16_t* __restrict__ B1,
             const bf16_t* __restrict__ B2,
             bf16_t* __restrict__ outQ,
             bf16_t* __restrict__ outK,
             bf16_t* __restrict__ outVt,
             float* __restrict__ outF,
             const int* __restrict__ pos) {
    constexpr int CP = 136;
    constexpr int SELEMS = (MODE == 0) ? (128 * CP) : 16384;
    __shared__ bf16_t smem[SELEMS];
    bf16_t* As = smem;            // [128][64] swizzled
    bf16_t* Bs = smem + 8192;     // [128][64] swizzled
    bf16_t* Cs = smem;            // epilogue overlay

    const int t = threadIdx.x;
    const int z = blockIdx.z;
    const bf16_t* Bm = (MODE == 0) ? (z == 0 ? B0 : (z == 1 ? B1 : B2)) : B0;

    const int m0 = blockIdx.x * 128;
    const int n0 = blockIdx.y * 128;
    const int lane = t & 63;
    const int w = t >> 6;
    const int wr = w >> 1;
    const int wc = w & 1;

    f32x4 acc[4][4] = {};

    const bf16_t* Ag = A + (size_t)m0 * KDIM;
    const bf16_t* Bg = Bm + (size_t)n0 * KDIM;

    const int rr = lane & 15;
    const int ko = (lane >> 4) * 8;

    int rI[4], cI[4];
#pragma unroll
    for (int c = 0; c < 4; ++c) {
        const int i = t + c * 256;
        rI[c] = i >> 3;
        cI[c] = ((i & 7) ^ (rI[c] & 7)) * 8;
    }

    for (int k0 = 0; k0 < KDIM; k0 += 64) {
#pragma unroll
        for (int c = 0; c < 4; ++c) {
            const int i = t + c * 256;
            gload_lds16(Ag + (size_t)rI[c] * KDIM + k0 + cI[c], &As[i * 8]);
        }
#pragma unroll
        for (int c = 0; c < 4; ++c) {
            const int i = t + c * 256;
            gload_lds16(Bg + (size_t)rI[c] * KDIM + k0 + cI[c], &Bs[i * 8]);
        }
        __syncthreads();

        bf16x8 af[2][4], bfr[2][4];
#pragma unroll
        for (int kk = 0; kk < 2; ++kk) {
#pragma unroll
            for (int m = 0; m < 4; ++m) {
                const int r = wr * 64 + m * 16 + rr;
                af[kk][m] = *reinterpret_cast<const bf16x8*>(
                    &As[r * 64 + ((kk * 32 + ko) ^ ((r & 7) * 8))]);
            }
#pragma unroll
            for (int n = 0; n < 4; ++n) {
                const int r = wc * 64 + n * 16 + rr;
                bfr[kk][n] = *reinterpret_cast<const bf16x8*>(
                    &Bs[r * 64 + ((kk * 32 + ko) ^ ((r & 7) * 8))]);
            }
        }
        __builtin_amdgcn_s_setprio(1);
#pragma unroll
        for (int kk = 0; kk < 2; ++kk)
#pragma unroll
            for (int m = 0; m < 4; ++m)
#pragma unroll
                for (int n = 0; n < 4; ++n)
                    acc[m][n] = MFMA(af[kk][m], bfr[kk][n], acc[m][n]);
        __builtin_amdgcn_s_setprio(0);
        __syncthreads();
    }

    const int rlb = wr * 64 + (lane >> 4) * 4;
    const int clb = wc * 64 + (lane & 15);

    if (MODE == 0) {
        if (z < 2) {
#pragma unroll
            for (int m = 0; m < 4; ++m)
#pragma unroll
                for (int n = 0; n < 4; ++n)
#pragma unroll
                    for (int j = 0; j < 4; ++j)
                        Cs[(rlb + m * 16 + j) * CP + clb + n * 16] = (__bf16)acc[m][n][j];
            __syncthreads();

            bf16_t* dst = (z == 0) ? outQ : outK;
            const int dch = t & 7;
            const int srow = t >> 3;
            float fr[4];
#pragma unroll
            for (int i = 0; i < 4; ++i)
                fr[i] = exp2f((float)(dch * 4 + i) * -0.4152410118609203f);
#pragma unroll
            for (int p = 0; p < 4; ++p) {
                const int s_loc = p * 32 + srow;
                const int gm = m0 + s_loc;
                const int bb = gm >> 11, sg = gm & (S_DIM - 1);
                const float pv = (float)pos[sg];
                float csv[4], snv[4];
#pragma unroll
                for (int i = 0; i < 4; ++i) {
                    const float a = pv * fr[i];
                    csv[i] = cosf(a); snv[i] = sinf(a);
                }
#pragma unroll
                for (int hc = 0; hc < 2; ++hc) {
                    const bf16x8 vv = *reinterpret_cast<const bf16x8*>(
                        &Cs[s_loc * CP + hc * 64 + dch * 8]);
                    bf16x8 ov;
#pragma unroll
                    for (int i = 0; i < 4; ++i) {
                        const float v0 = (float)vv[2 * i], v1 = (float)vv[2 * i + 1];
                        ov[2 * i]     = (__bf16)(v0 * csv[i] - v1 * snv[i]);
                        ov[2 * i + 1] = (__bf16)(v0 * snv[i] + v1 * csv[i]);
                    }
                    const int h = (n0 >> 6) + hc;
                    *reinterpret_cast<bf16x8*>(
                        &dst[((size_t)(bb * H_DIM + h) * S_DIM + sg) * 64 + dch * 8]) = ov;
                }
            }
        } else {
#pragma unroll
            for (int m = 0; m < 4; ++m)
#pragma unroll
                for (int n = 0; n < 4; ++n) {
                    const int cl = clb + n * 16;
                    bf16x4 v4;
#pragma unroll
                    for (int j = 0; j < 4; ++j) v4[j] = (__bf16)acc[m][n][j];
                    *reinterpret_cast<bf16x4*>(&Cs[cl * CP + rlb + m * 16]) = v4;
                }
            __syncthreads();

            const int cl = t >> 1, sh = t & 1;
            const int cg = n0 + cl, h = cg >> 6, d = cg & 63;
            const int bb = m0 >> 11, s0g = m0 & (S_DIM - 1);
            bf16_t* vdst = &outVt[((size_t)(bb * H_DIM + h) * DK + d) * S_DIM + s0g + sh * 64];
#pragma unroll
            for (int i = 0; i < 8; ++i)
                *reinterpret_cast<bf16x8*>(&vdst[i * 8]) =
                    *reinterpret_cast<const bf16x8*>(&Cs[cl * CP + sh * 64 + i * 8]);
        }
    } else {
        const int rbase = m0 + rlb;
        const int cbase = n0 + clb;
#pragma unroll
        for (int m = 0; m < 4; ++m)
#pragma unroll
            for (int n = 0; n < 4; ++n)
#pragma unroll
                for (int j = 0; j < 4; ++j)
                    outF[(size_t)(rbase + m * 16 + j) * DM + cbase + n * 16] = acc[m][n][j];
    }
}

// ---------------- causal flash attention v11 (R15-exact, proven 46.4 us) ----------
__global__ __launch_bounds__(256, 4)
void attn_kernel(const bf16_t* __restrict__ Q, const bf16_t* __restrict__ Kg,
                 const bf16_t* __restrict__ Vt, bf16_t* __restrict__ O) {
    __shared__ bf16_t Ks[2][64 * 64];
    __shared__ bf16_t Vs[2][64 * 64];
    __shared__ bf16_t P_lds[4][16 * 64];

    const int t = threadIdx.x;
    const int lane = t & 63;
    const int w = t >> 6;                  // 0..3
    const int qbo = blockIdx.x >> 5;       // 0..31 (longest first)
    const int qb = 31 - qbo;
    const int bh = blockIdx.x & 31;
    const int q0 = qb * 64 + w * 16;
    const int b = bh >> 4, h = bh & 15;
    const int rr = lane & 15;
    const int hi = lane >> 4;
    const int psw = (rr & 7) * 8;          // P col XOR swizzle

    const bf16_t* Kbh = Kg + (size_t)bh * S_DIM * DK;
    const bf16_t* Vbh = Vt + (size_t)bh * DK * S_DIM;   // [d][s]
    bf16_t* Pw = P_lds[w];

    const int i0 = t, i1 = t + 256;
    const int r0 = i0 >> 3, c0 = ((i0 & 7) ^ (r0 & 7)) * 8;
    const int r1 = i1 >> 3, c1 = ((i1 & 7) ^ (r1 & 7)) * 8;

    // Q fragments, folded scale = (1/8) * log2(e)
    const float QSCALE = 0.18033688011112042f;
    const bf16_t* Qp = Q + ((size_t)bh * S_DIM + q0) * DK;
    bf16x8 qf[2];
    qf[0] = *reinterpret_cast<const bf16x8*>(&Qp[rr * DK + hi * 8]);
    qf[1] = *reinterpret_cast<const bf16x8*>(&Qp[rr * DK + 32 + hi * 8]);
#pragma unroll
    for (int i = 0; i < 8; ++i) {
        qf[0][i] = (__bf16)((float)qf[0][i] * QSCALE);
        qf[1][i] = (__bf16)((float)qf[1][i] * QSCALE);
    }

    bf16x8 ones;
#pragma unroll
    for (int i = 0; i < 8; ++i) ones[i] = (__bf16)1.0f;

    f32x4 o[4] = {};
    f32x4 la = {};
    float m = -INFINITY;

    const int nt = qb + 1;

    gload_lds16(Kbh + (size_t)r0 * DK + c0, &Ks[0][i0 * 8]);
    gload_lds16(Kbh + (size_t)r1 * DK + c1, &Ks[0][i1 * 8]);
    gload_lds16(Vbh + (size_t)r0 * S_DIM + c0, &Vs[0][i0 * 8]);
    gload_lds16(Vbh + (size_t)r1 * S_DIM + c1, &Vs[0][i1 * 8]);
    __syncthreads();

    for (int tt = 0; tt < nt; ++tt) {
        const int cur = tt & 1;
        const int kv0 = tt * 64;

        if (tt + 1 < nt) {
            const int kv1 = kv0 + 64;
            bf16_t* Kn = Ks[cur ^ 1];
            bf16_t* Vn = Vs[cur ^ 1];
            gload_lds16(Kbh + (size_t)(kv1 + r0) * DK + c0, &Kn[i0 * 8]);
            gload_lds16(Kbh + (size_t)(kv1 + r1) * DK + c1, &Kn[i1 * 8]);
            gload_lds16(Vbh + (size_t)r0 * S_DIM + kv1 + c0, &Vn[i0 * 8]);
            gload_lds16(Vbh + (size_t)r1 * S_DIM + kv1 + c1, &Vn[i1 * 8]);
        }
        const bf16_t* Kc = Ks[cur];
        const bf16_t* Vc = Vs[cur];

        // QK^T: s[t16][j] = S[kv = t16*16 + hi*4 + j][q = rr]
        f32x4 s[4] = {};
        __builtin_amdgcn_s_setprio(1);
#pragma unroll
        for (int t16 = 0; t16 < 4; ++t16) {
            const int r = t16 * 16 + rr;
            const int sw = (r & 7) * 8;
            bf16x8 kf0 = *reinterpret_cast<const bf16x8*>(&Kc[r * 64 + ((hi * 8) ^ sw)]);
            bf16x8 kf1 = *reinterpret_cast<const bf16x8*>(&Kc[r * 64 + ((32 + hi * 8) ^ sw)]);
            s[t16] = MFMA(kf0, qf[0], s[t16]);
            s[t16] = MFMA(kf1, qf[1], s[t16]);
        }
        __builtin_amdgcn_s_setprio(0);

        if (tt == qb) {
            const int qg = q0 + rr;
#pragma unroll
            for (int t16 = 0; t16 < 4; ++t16)
#pragma unroll
                for (int j = 0; j < 4; ++j)
                    if (kv0 + t16 * 16 + hi * 4 + j > qg) s[t16][j] = -INFINITY;
        }

        // softmax (lane-local defer-max trip, THR=8; l via ones-MFMA)
        f32x4 mv = s[0];
#pragma unroll
        for (int t16 = 1; t16 < 4; ++t16) {
            mv[0] = fmaxf(mv[0], s[t16][0]); mv[1] = fmaxf(mv[1], s[t16][1]);
            mv[2] = fmaxf(mv[2], s[t16][2]); mv[3] = fmaxf(mv[3], s[t16][3]);
        }
        const float mloc = fmaxf(fmaxf(mv[0], mv[1]), fmaxf(mv[2], mv[3]));
        if (__any(mloc - m > 8.0f)) {
            float mf = fmaxf(mloc, __shfl_xor(mloc, 16));
            mf = fmaxf(mf, __shfl_xor(mf, 32));
            const float mnew = fmaxf(m, mf);
            const float scale = exp2f(m - mnew);
#pragma unroll
            for (int i = 0; i < 4; ++i) la[i] *= scale;
#pragma unroll
            for (int db = 0; db < 4; ++db)
#pragma unroll
                for (int j = 0; j < 4; ++j) o[db][j] *= scale;
            m = mnew;
        }
#pragma unroll
        for (int t16 = 0; t16 < 4; ++t16) {
            bf16x4 pb;
#pragma unroll
            for (int j = 0; j < 4; ++j) pb[j] = (__bf16)exp2f(s[t16][j] - m);
            *reinterpret_cast<bf16x4*>(&Pw[rr * 64 + ((t16 * 16 + hi * 4) ^ psw)]) = pb;
        }

        bf16x8 pf0 = *reinterpret_cast<const bf16x8*>(&Pw[rr * 64 + ((hi * 8) ^ psw)]);
        bf16x8 pf1 = *reinterpret_cast<const bf16x8*>(&Pw[rr * 64 + ((32 + hi * 8) ^ psw)]);
        __builtin_amdgcn_s_setprio(1);
        la = MFMA(ones, pf0, la);
        la = MFMA(ones, pf1, la);
#pragma unroll
        for (int db = 0; db < 4; ++db) {
            const int vr = db * 16 + rr;
            const int sw = (vr & 7) * 8;
            bf16x8 vf0 = *reinterpret_cast<const bf16x8*>(&Vc[vr * 64 + ((hi * 8) ^ sw)]);
            bf16x8 vf1 = *reinterpret_cast<const bf16x8*>(&Vc[vr * 64 + ((32 + hi * 8) ^ sw)]);
            o[db] = MFMA(vf0, pf0, o[db]);
            o[db] = MFMA(vf1, pf1, o[db]);
        }
        __builtin_amdgcn_s_setprio(0);

        __syncthreads();
    }

    const float linv = 1.0f / la[0];
#pragma unroll
    for (int db = 0; db < 4; ++db) {
        bf16x4 ov;
#pragma unroll
        for (int j = 0; j < 4; ++j) ov[j] = (__bf16)(o[db][j] * linv);
        *reinterpret_cast<bf16x4*>(
            &O[((size_t)(b * S_DIM + q0 + rr)) * DM + h * DK + db * 16 + hi * 4]) = ov;
    }
}

extern "C" void kernel_launch(void* const* d_in, const int* in_sizes, int n_in,
                              void* d_out, int out_size, void* d_ws, size_t ws_size,
                              hipStream_t stream) {
    const float* x  = (const float*)d_in[0];
    const float* Wq = (const float*)d_in[1];
    const float* Wk = (const float*)d_in[2];
    const float* Wv = (const float*)d_in[3];
    const float* Wo = (const float*)d_in[4];
    const int* pos  = (const int*)d_in[5];
    float* out = (float*)d_out;

    char* ws = (char*)d_ws;
    bf16_t* xb  = (bf16_t*)(ws);
    bf16_t* Wqb = (bf16_t*)(ws + (8u << 20));
    bf16_t* Wkb = (bf16_t*)(ws + (10u << 20));
    bf16_t* Wvb = (bf16_t*)(ws + (12u << 20));
    bf16_t* Wob = (bf16_t*)(ws + (14u << 20));
    bf16_t* Qb  = (bf16_t*)(ws + (16u << 20));
    bf16_t* Kb  = (bf16_t*)(ws + (24u << 20));
    bf16_t* Vtb = (bf16_t*)(ws + (32u << 20));
    bf16_t* Ab  = (bf16_t*)(ws);  // reuse xb region after QKV GEMM

    const int NX = B_DIM * S_DIM * DM;
    const int NW = DM * DM;
    const int NTOT = NX + 4 * NW;  // 8388608

    cvt_all<<<NTOT / 1024, 256, 0, stream>>>(x, Wq, Wk, Wv, Wo,
                                             xb, Wqb, Wkb, Wvb, Wob);

    gemm_bt<0><<<dim3(32, 8, 3), 256, 0, stream>>>(xb, Wqb, Wkb, Wvb,
                                                   Qb, Kb, Vtb, nullptr, pos);

    attn_kernel<<<B_DIM * H_DIM * 32, 256, 0, stream>>>(Qb, Kb, Vtb, Ab);

    gemm_bt<1><<<dim3(32, 8, 1), 256, 0, stream>>>(Ab, Wob, nullptr, nullptr,
                                                   nullptr, nullptr, nullptr, out, pos);
}